// Round 17
// baseline (126.209 us; speedup 1.0000x reference)
//
#include <hip/hip_runtime.h>
#include <hip/hip_bf16.h>
#include <math.h>

#define TOK_TOTAL 16384
#define D_MODEL   2048
#define NEXP      64
#define BM        32               // tokens per block
#define KC        64               // k per chunk
#define NCH       (D_MODEL / KC)   // 32
#define NBLK      (TOK_TOTAL / BM) // 512
#define TAU       1e-3f

#define IDX_OFF   (TOK_TOTAL * NEXP)
#define LOSS_OFF  (IDX_OFF + TOK_TOTAL * 2)

// ws (floats): XH8 [8.4M] | XL8 | WH8 | WL8 | cntp | rep_cnt | rep_list
#define NX8       (TOK_TOTAL * 256)          // 4,194,304 short8 entries
#define WS_XH     0
#define WS_XL     (NX8 * 4)                  // float offsets (short8 = 4 floats)
#define WS_WH     (2 * NX8 * 4)
#define WS_WL     (WS_WH + 65536)
#define WS_CNTP   (WS_WL + 65536)
#define WS_RCNT   (WS_CNTP + NBLK * NEXP)
#define WS_RLIST  (WS_RCNT + 1)

typedef __attribute__((ext_vector_type(8))) short short8_t;
typedef __attribute__((ext_vector_type(4))) float f32x4;

__device__ __forceinline__ short cvh(float f) {
    return __builtin_bit_cast(short, __float2bfloat16(f));
}
__device__ __forceinline__ short cvl(float f) {
    __hip_bfloat16 h = __float2bfloat16(f);
    return __builtin_bit_cast(short, __float2bfloat16(f - __bfloat162float(h)));
}

__device__ __forceinline__ void gload16(const void* gp, void* lp) {
    __builtin_amdgcn_global_load_lds(
        (const __attribute__((address_space(1))) void*)gp,
        (__attribute__((address_space(3))) void*)lp, 16, 0, 0);
}

// ---- K0a: THE EXPERIMENT — pure stream-order nt-read of x, write split-bf16 ----
__global__ __launch_bounds__(256, 8)
void prep_x(const float* __restrict__ x, short8_t* __restrict__ XH8,
            short8_t* __restrict__ XL8, int* __restrict__ rep_cnt)
{
    const int tid = blockIdx.x * 256 + threadIdx.x;     // 2048 blocks
    if (tid == 0) *rep_cnt = 0;
    const f32x4* x4 = (const f32x4*)x;
    #pragma unroll
    for (int i = 0; i < 8; ++i) {
        const long g8 = (long)tid + (long)i * (2048 * 256);
        f32x4 a = __builtin_nontemporal_load(x4 + g8 * 2);
        f32x4 b = __builtin_nontemporal_load(x4 + g8 * 2 + 1);
        short8_t h8, l8;
        h8[0]=cvh(a[0]); h8[1]=cvh(a[1]); h8[2]=cvh(a[2]); h8[3]=cvh(a[3]);
        h8[4]=cvh(b[0]); h8[5]=cvh(b[1]); h8[6]=cvh(b[2]); h8[7]=cvh(b[3]);
        l8[0]=cvl(a[0]); l8[1]=cvl(a[1]); l8[2]=cvl(a[2]); l8[3]=cvl(a[3]);
        l8[4]=cvl(b[0]); l8[5]=cvl(b[1]); l8[6]=cvl(b[2]); l8[7]=cvl(b[3]);
        XH8[g8] = h8;
        XL8[g8] = l8;
    }
}

// ---- K0b: split-bf16 W table, k8-major ----
__global__ __launch_bounds__(256, 1)
void build_wt(const float* __restrict__ W, short8_t* __restrict__ WH8,
              short8_t* __restrict__ WL8)
{
    const int id = blockIdx.x * 256 + threadIdx.x;
    const int k8 = id & 255, e = id >> 8;
    float4 a = *(const float4*)(W + (long)e * D_MODEL + k8 * 8);
    float4 b = *(const float4*)(W + (long)e * D_MODEL + k8 * 8 + 4);
    short8_t h8, l8;
    h8[0]=cvh(a.x); h8[1]=cvh(a.y); h8[2]=cvh(a.z); h8[3]=cvh(a.w);
    h8[4]=cvh(b.x); h8[5]=cvh(b.y); h8[6]=cvh(b.z); h8[7]=cvh(b.w);
    l8[0]=cvl(a.x); l8[1]=cvl(a.y); l8[2]=cvl(a.z); l8[3]=cvl(a.w);
    l8[4]=cvl(b.x); l8[5]=cvl(b.y); l8[6]=cvl(b.z); l8[7]=cvl(b.w);
    WH8[k8 * NEXP + e] = h8;
    WL8[k8 * NEXP + e] = l8;
}

// ---- K1: gload_lds MFMA GEMM from split tables (no cvt in K-loop) -----------
__global__ __launch_bounds__(256, 2)
void router_gemm(const short8_t* __restrict__ XH8, const short8_t* __restrict__ XL8,
                 const short8_t* __restrict__ WH8, const short8_t* __restrict__ WL8,
                 float* __restrict__ out, float* __restrict__ cntp,
                 int* __restrict__ rep_cnt, int* __restrict__ rep_list)
{
    // smem carve (shorts): sxh [2][32][64] | sxl | swh [2][8][64]sh8 | swl
    __shared__ __align__(16) short smem[24576];          // 48 KB
    __shared__ float4 s_ig[BM];
    short* sxh = smem;                                   // 4096 shorts
    short* sxl = smem + 4096;                            // 4096
    short8_t* swh = (short8_t*)(smem + 8192);            // 1024 short8
    short8_t* swl = (short8_t*)(smem + 16384);           // 1024 short8

    const int t = threadIdx.x;
    const int w = t >> 6, l = t & 63;
    const int tg = w >> 1, eg = w & 1;
    const int lane16 = l & 15, kq = l >> 4;
    const long tok0 = (long)blockIdx.x * BM;
    const int arow = tg * 16 + lane16;

    f32x4 acc0 = (f32x4){0.f,0.f,0.f,0.f};
    f32x4 acc1 = (f32x4){0.f,0.f,0.f,0.f};

    auto STAGE = [&](int c, int buf) {
        // x: 1 gload16/lane each for h,l: row r = w*8 + (l>>3), slot swz source
        {
            const int r  = w * 8 + (l >> 3);
            const int s  = (l & 7) ^ (r & 7);
            const long src = (tok0 + r) * 256 + c * 8 + s;
            gload16(XH8 + src, sxh + (buf * 32 + w * 8) * 64);
            gload16(XL8 + src, sxl + (buf * 32 + w * 8) * 64);
        }
        // W: linear, k8 rows w*2, w*2+1
        #pragma unroll
        for (int j = 0; j < 2; ++j) {
            const int k8 = w * 2 + j;
            gload16(WH8 + ((long)c * 8 + k8) * NEXP + l, swh + (buf * 8 + k8) * NEXP);
            gload16(WL8 + ((long)c * 8 + k8) * NEXP + l, swl + (buf * 8 + k8) * NEXP);
        }
    };

    auto COMPUTE = [&](int buf) {
        #pragma unroll
        for (int seg = 0; seg < 2; ++seg) {
            const int slot = (seg * 4 + kq) ^ (arow & 7);
            short8_t ah = *(const short8_t*)(sxh + (buf * 32 + arow) * 64 + slot * 8);
            short8_t al = *(const short8_t*)(sxl + (buf * 32 + arow) * 64 + slot * 8);
            const int k8 = seg * 4 + kq;
            short8_t bh0 = swh[(buf * 8 + k8) * NEXP + eg * 32 + lane16];
            short8_t bl0 = swl[(buf * 8 + k8) * NEXP + eg * 32 + lane16];
            short8_t bh1 = swh[(buf * 8 + k8) * NEXP + eg * 32 + 16 + lane16];
            short8_t bl1 = swl[(buf * 8 + k8) * NEXP + eg * 32 + 16 + lane16];
            acc0 = __builtin_amdgcn_mfma_f32_16x16x32_bf16(ah, bl0, acc0, 0, 0, 0);
            acc0 = __builtin_amdgcn_mfma_f32_16x16x32_bf16(al, bh0, acc0, 0, 0, 0);
            acc0 = __builtin_amdgcn_mfma_f32_16x16x32_bf16(ah, bh0, acc0, 0, 0, 0);
            acc1 = __builtin_amdgcn_mfma_f32_16x16x32_bf16(ah, bl1, acc1, 0, 0, 0);
            acc1 = __builtin_amdgcn_mfma_f32_16x16x32_bf16(al, bh1, acc1, 0, 0, 0);
            acc1 = __builtin_amdgcn_mfma_f32_16x16x32_bf16(ah, bh1, acc1, 0, 0, 0);
        }
    };

    STAGE(0, 0);
    __syncthreads();

    for (int c = 0; c < NCH; ++c) {
        const int buf = c & 1;
        if (c + 1 < NCH) STAGE(c + 1, buf ^ 1);
        COMPUTE(buf);
        __syncthreads();
    }

    // ---- logits -> LDS (alias smem start; stride 67 = conflict-free scan) ----
    float* Lg = (float*)smem;                 // [32][67] floats = 8576 B
    {
        const int trow = tg * 16 + kq * 4;
        #pragma unroll
        for (int r = 0; r < 4; ++r) {
            Lg[(trow + r) * 67 + eg * 32 + lane16]      = acc0[r];
            Lg[(trow + r) * 67 + eg * 32 + 16 + lane16] = acc1[r];
        }
    }
    __syncthreads();

    if (t < BM) {
        const float* lrow = Lg + t * 67;
        float b0 = -1e30f, b1 = -1e30f, b2 = -1e30f;
        int i0 = 0, i1 = 0;
        for (int e = 0; e < NEXP; ++e) {
            float v = lrow[e];
            if (v > b0)      { b2 = b1; b1 = b0; i1 = i0; b0 = v; i0 = e; }
            else if (v > b1) { b2 = b1; b1 = v; i1 = e; }
            else if (v > b2) { b2 = v; }
        }
        float ex = __expf(b1 - b0);
        float g0 = 1.f / (1.f + ex);
        long tok = tok0 + t;
        out[IDX_OFF + 2 * tok]     = (float)i0;
        out[IDX_OFF + 2 * tok + 1] = (float)i1;
        s_ig[t] = make_float4((float)i0, (float)i1, g0, ex * g0);
        if ((b0 - b1 < TAU) || (b1 - b2 < TAU)) {
            int p = atomicAdd(rep_cnt, 1);
            rep_list[p] = (int)tok;
        }
    }
    __syncthreads();

    {
        const int r8 = t >> 3, e0 = (t & 7) * 8;
        float4 gg = s_ig[r8];
        const int i0 = (int)gg.x, i1 = (int)gg.y;
        float v[8];
        #pragma unroll
        for (int j = 0; j < 8; ++j) {
            int e = e0 + j;
            v[j] = (e == i0) ? gg.z : ((e == i1) ? gg.w : 0.f);
        }
        float* orow = out + (tok0 + r8) * NEXP + e0;
        *(float4*)(orow)     = make_float4(v[0], v[1], v[2], v[3]);
        *(float4*)(orow + 4) = make_float4(v[4], v[5], v[6], v[7]);
    }

    if (t < NEXP) {
        float cs = 0.f;
        for (int tt = 0; tt < BM; ++tt) {
            float4 gg = s_ig[tt];
            if ((int)gg.x == t) cs += gg.z;
            if ((int)gg.y == t) cs += gg.w;
        }
        cntp[blockIdx.x * NEXP + t] = cs;
    }
}

// -------- K2: fused tail: block 0 = loss; blocks 1.. = fp64 index repair ------
__global__ __launch_bounds__(256, 1)
void router_tail(const float* __restrict__ x, const float* __restrict__ W,
                 float* __restrict__ out, const float* __restrict__ cntp,
                 const int* __restrict__ rep_cnt, const int* __restrict__ rep_list)
{
    const int t = threadIdx.x;

    if (blockIdx.x == 0) {
        __shared__ double red[4][NEXP];
        const int e = t & 63, p = t >> 6;
        double s = 0.0;
        for (int b = 0; b < NBLK / 4; ++b)
            s += (double)cntp[(p * (NBLK / 4) + b) * NEXP + e];
        red[p][e] = s;
        __syncthreads();
        if (t == 0) {
            double sc[NEXP], tot = 0.0;
            for (int i = 0; i < NEXP; ++i) {
                sc[i] = red[0][i] + red[1][i] + red[2][i] + red[3][i];
                tot += sc[i];
            }
            double loss = 0.0;
            for (int i = 0; i < NEXP; ++i) {
                double d = sc[i] / tot * (double)NEXP - 1.0;
                loss += d * d;
            }
            out[LOSS_OFF] = (float)(loss / NEXP);
        }
        return;
    }

    __shared__ double red[4][NEXP];
    const int nf = *rep_cnt;
    const int e = t & 63, part = t >> 6;
    for (int i = (int)blockIdx.x - 1; i < nf; i += (int)gridDim.x - 1) {
        const long tok = rep_list[i];
        const float* xr = x + tok * D_MODEL;
        const float* wr = W + (long)e * D_MODEL;
        const int k0 = part * 512;
        double s = 0.0;
        for (int kk = 0; kk < 512; kk += 4) {
            float4 xv = *(const float4*)(xr + k0 + kk);
            float4 wv = *(const float4*)(wr + k0 + kk);
            s = fma((double)xv.x, (double)wv.x, s);
            s = fma((double)xv.y, (double)wv.y, s);
            s = fma((double)xv.z, (double)wv.z, s);
            s = fma((double)xv.w, (double)wv.w, s);
        }
        red[part][e] = s;
        __syncthreads();
        if (t == 0) {
            double best = -1e300, sec = -1e300;
            int bi = 0, si = 0;
            for (int ee = 0; ee < NEXP; ++ee) {
                double vv = red[0][ee] + red[1][ee] + red[2][ee] + red[3][ee];
                if (vv > best)     { sec = best; si = bi; best = vv; bi = ee; }
                else if (vv > sec) { sec = vv; si = ee; }
            }
            out[IDX_OFF + 2 * tok]     = (float)bi;
            out[IDX_OFF + 2 * tok + 1] = (float)si;
        }
        __syncthreads();
    }
}

extern "C" void kernel_launch(void* const* d_in, const int* in_sizes, int n_in,
                              void* d_out, int out_size, void* d_ws, size_t ws_size,
                              hipStream_t stream)
{
    const float* x = (const float*)d_in[0];
    const float* W = (const float*)d_in[1];
    float* out = (float*)d_out;
    float* ws  = (float*)d_ws;         // ~135 MB used
    short8_t* XH8 = (short8_t*)(ws + WS_XH);
    short8_t* XL8 = (short8_t*)(ws + WS_XL);
    short8_t* WH8 = (short8_t*)(ws + WS_WH);
    short8_t* WL8 = (short8_t*)(ws + WS_WL);
    float* cntp = ws + WS_CNTP;
    int* rep_cnt  = (int*)(ws + WS_RCNT);
    int* rep_list = (int*)(ws + WS_RLIST);

    prep_x     <<<2048, 256, 0, stream>>>(x, XH8, XL8, rep_cnt);
    build_wt   <<<64, 256, 0, stream>>>(W, WH8, WL8);
    router_gemm<<<NBLK, 256, 0, stream>>>(XH8, XL8, WH8, WL8, out, cntp, rep_cnt, rep_list);
    router_tail<<<257, 256, 0, stream>>>(x, W, out, cntp, rep_cnt, rep_list);
}

// Round 18
// 122.250 us; speedup vs baseline: 1.0324x; 1.0324x over previous
//
#include <hip/hip_runtime.h>
#include <hip/hip_bf16.h>
#include <math.h>

#define TOK_TOTAL 16384
#define D_MODEL   2048
#define NEXP      64
#define BM        16               // tokens per block, full K resident
#define NBLK      (TOK_TOTAL / BM) // 1024
#define TAU       1e-3f

#define IDX_OFF   (TOK_TOTAL * NEXP)
#define LOSS_OFF  (IDX_OFF + TOK_TOTAL * 2)

// ws (floats): WH8 [1MB] | WL8 [1MB] | cntp [1024*64] | rep_cnt | rep_list
#define WS_WL     65536
#define WS_CNTP   (2 * 65536)
#define WS_RCNT   (WS_CNTP + NBLK * NEXP)
#define WS_RLIST  (WS_RCNT + 1)

typedef __attribute__((ext_vector_type(8))) short short8_t;
typedef __attribute__((ext_vector_type(4))) float f32x4;

__device__ __forceinline__ short cvh(float f) {
    return __builtin_bit_cast(short, __float2bfloat16(f));
}
__device__ __forceinline__ short cvl(float f) {
    __hip_bfloat16 h = __float2bfloat16(f);
    return __builtin_bit_cast(short, __float2bfloat16(f - __bfloat162float(h)));
}

__device__ __forceinline__ void gload16(const void* gp, void* lp) {
    __builtin_amdgcn_global_load_lds(
        (const __attribute__((address_space(1))) void*)gp,
        (__attribute__((address_space(3))) void*)lp, 16, 0, 0);
}

// ---- K0: split-bf16 W table, k8-major: WH8[k8][e] = bf16hi(W[e][8k8..+7]) ----
__global__ __launch_bounds__(256, 1)
void build_wt(const float* __restrict__ W, short8_t* __restrict__ WH8,
              short8_t* __restrict__ WL8, int* __restrict__ rep_cnt)
{
    const int id = blockIdx.x * 256 + threadIdx.x;
    if (id == 0) *rep_cnt = 0;
    const int k8 = id & 255, e = id >> 8;
    float4 a = *(const float4*)(W + (long)e * D_MODEL + k8 * 8);
    float4 b = *(const float4*)(W + (long)e * D_MODEL + k8 * 8 + 4);
    short8_t h8, l8;
    h8[0]=cvh(a.x); h8[1]=cvh(a.y); h8[2]=cvh(a.z); h8[3]=cvh(a.w);
    h8[4]=cvh(b.x); h8[5]=cvh(b.y); h8[6]=cvh(b.z); h8[7]=cvh(b.w);
    l8[0]=cvl(a.x); l8[1]=cvl(a.y); l8[2]=cvl(a.z); l8[3]=cvl(a.w);
    l8[4]=cvl(b.x); l8[5]=cvl(b.y); l8[6]=cvl(b.z); l8[7]=cvl(b.w);
    WH8[k8 * NEXP + e] = h8;
    WL8[k8 * NEXP + e] = l8;
}

// ---- K1: stream-staged full-K MFMA GEMM + fused epilogue --------------------
// 512 threads (8 waves): wave w -> expert group g=w&3 (16 experts), K half h=w>>2
__global__ __launch_bounds__(512, 1)
void router_gemm(const float* __restrict__ x,
                 const short8_t* __restrict__ WH8, const short8_t* __restrict__ WL8,
                 float* __restrict__ out, float* __restrict__ cntp,
                 int* __restrict__ rep_cnt, int* __restrict__ rep_list)
{
    __shared__ __align__(16) float sx[BM][D_MODEL];   // 128 KB, linear stream dest
    __shared__ float  Lg[BM][68];                     // logits
    __shared__ float4 s_ig[BM];

    const int t = threadIdx.x;
    const int w = t >> 6, l = t & 63;
    const int g = w & 3, h = w >> 2;
    const int lane16 = l & 15, kq = l >> 4;
    const long tok0 = (long)blockIdx.x * BM;

    // ---- STAGE: pure stream. 8192 float4 slots; inst i of wave w covers
    // slots i*512 + w*64 + [0..63] -> 1 KB contiguous global per instruction.
    {
        const float4* xs = (const float4*)x + tok0 * (D_MODEL / 4);
        float4* sx4 = (float4*)&sx[0][0];
        #pragma unroll
        for (int i = 0; i < 16; ++i) {
            const int base = i * 512 + w * 64;
            gload16(xs + base + l, sx4 + base);
        }
    }
    __syncthreads();

    // ---- K loop: no barriers, no global x. W streamed from L2 tables. ----
    f32x4 acc = (f32x4){0.f, 0.f, 0.f, 0.f};
    const short8_t* WHp = WH8 + g * 16 + lane16;
    const short8_t* WLp = WL8 + g * 16 + lane16;
    const int ks0 = h * 32;
    #pragma unroll 4
    for (int ks = ks0; ks < ks0 + 32; ++ks) {
        const int kk = ks * 32 + kq * 8;
        f32x4 fa = *(const f32x4*)&sx[lane16][kk];
        f32x4 fb = *(const f32x4*)&sx[lane16][kk + 4];
        short8_t ah, al;
        ah[0]=cvh(fa[0]); ah[1]=cvh(fa[1]); ah[2]=cvh(fa[2]); ah[3]=cvh(fa[3]);
        ah[4]=cvh(fb[0]); ah[5]=cvh(fb[1]); ah[6]=cvh(fb[2]); ah[7]=cvh(fb[3]);
        al[0]=cvl(fa[0]); al[1]=cvl(fa[1]); al[2]=cvl(fa[2]); al[3]=cvl(fa[3]);
        al[4]=cvl(fb[0]); al[5]=cvl(fb[1]); al[6]=cvl(fb[2]); al[7]=cvl(fb[3]);
        const long k8 = (long)(ks * 4 + kq) * NEXP;
        short8_t bh = WHp[k8];
        short8_t bl = WLp[k8];
        acc = __builtin_amdgcn_mfma_f32_16x16x32_bf16(ah, bl, acc, 0, 0, 0);
        acc = __builtin_amdgcn_mfma_f32_16x16x32_bf16(al, bh, acc, 0, 0, 0);
        acc = __builtin_amdgcn_mfma_f32_16x16x32_bf16(ah, bh, acc, 0, 0, 0);
    }

    // ---- combine K halves: token = kq*4+r, expert = g*16+lane16 ----
    if (h == 0) {
        #pragma unroll
        for (int r = 0; r < 4; ++r)
            Lg[kq * 4 + r][g * 16 + lane16] = acc[r];
    }
    __syncthreads();
    if (h == 1) {
        #pragma unroll
        for (int r = 0; r < 4; ++r)
            Lg[kq * 4 + r][g * 16 + lane16] += acc[r];
    }
    __syncthreads();

    // ---- top-3, idx, flags ----
    if (t < BM) {
        const float* lrow = Lg[t];
        float b0 = -1e30f, b1 = -1e30f, b2 = -1e30f;
        int i0 = 0, i1 = 0;
        for (int e = 0; e < NEXP; ++e) {
            float v = lrow[e];
            if (v > b0)      { b2 = b1; b1 = b0; i1 = i0; b0 = v; i0 = e; }
            else if (v > b1) { b2 = b1; b1 = v; i1 = e; }
            else if (v > b2) { b2 = v; }
        }
        float ex = __expf(b1 - b0);
        float g0 = 1.f / (1.f + ex);
        long tok = tok0 + t;
        out[IDX_OFF + 2 * tok]     = (float)i0;
        out[IDX_OFF + 2 * tok + 1] = (float)i1;
        s_ig[t] = make_float4((float)i0, (float)i1, g0, ex * g0);
        if ((b0 - b1 < TAU) || (b1 - b2 < TAU)) {
            int p = atomicAdd(rep_cnt, 1);
            rep_list[p] = (int)tok;
        }
    }
    __syncthreads();

    // ---- dense gates: 16 lanes per token, 4 floats each (512 thr = 16x16x... )
    if (t < 256) {
        const int r = t >> 4, e0 = (t & 15) * 4;
        float4 gg = s_ig[r];
        const int i0 = (int)gg.x, i1 = (int)gg.y;
        float v[4];
        #pragma unroll
        for (int j = 0; j < 4; ++j) {
            int e = e0 + j;
            v[j] = (e == i0) ? gg.z : ((e == i1) ? gg.w : 0.f);
        }
        *(float4*)(out + (tok0 + r) * NEXP + e0) = make_float4(v[0], v[1], v[2], v[3]);
    }

    // ---- per-block expert counts ----
    if (t < NEXP) {
        float cs = 0.f;
        for (int tt = 0; tt < BM; ++tt) {
            float4 gg = s_ig[tt];
            if ((int)gg.x == t) cs += gg.z;
            if ((int)gg.y == t) cs += gg.w;
        }
        cntp[blockIdx.x * NEXP + t] = cs;
    }
}

// -------- K2: fused tail: block 0 = loss; blocks 1.. = fp64 index repair ------
__global__ __launch_bounds__(256, 1)
void router_tail(const float* __restrict__ x, const float* __restrict__ W,
                 float* __restrict__ out, const float* __restrict__ cntp,
                 const int* __restrict__ rep_cnt, const int* __restrict__ rep_list)
{
    const int t = threadIdx.x;

    if (blockIdx.x == 0) {
        __shared__ double red[4][NEXP];
        const int e = t & 63, p = t >> 6;
        double s = 0.0;
        for (int b = 0; b < NBLK / 4; ++b)
            s += (double)cntp[(p * (NBLK / 4) + b) * NEXP + e];
        red[p][e] = s;
        __syncthreads();
        if (t == 0) {
            double sc[NEXP], tot = 0.0;
            for (int i = 0; i < NEXP; ++i) {
                sc[i] = red[0][i] + red[1][i] + red[2][i] + red[3][i];
                tot += sc[i];
            }
            double loss = 0.0;
            for (int i = 0; i < NEXP; ++i) {
                double d = sc[i] / tot * (double)NEXP - 1.0;
                loss += d * d;
            }
            out[LOSS_OFF] = (float)(loss / NEXP);
        }
        return;
    }

    __shared__ double red[4][NEXP];
    const int nf = *rep_cnt;
    const int e = t & 63, part = t >> 6;
    for (int i = (int)blockIdx.x - 1; i < nf; i += (int)gridDim.x - 1) {
        const long tok = rep_list[i];
        const float* xr = x + tok * D_MODEL;
        const float* wr = W + (long)e * D_MODEL;
        const int k0 = part * 512;
        double s = 0.0;
        for (int kk = 0; kk < 512; kk += 4) {
            float4 xv = *(const float4*)(xr + k0 + kk);
            float4 wv = *(const float4*)(wr + k0 + kk);
            s = fma((double)xv.x, (double)wv.x, s);
            s = fma((double)xv.y, (double)wv.y, s);
            s = fma((double)xv.z, (double)wv.z, s);
            s = fma((double)xv.w, (double)wv.w, s);
        }
        red[part][e] = s;
        __syncthreads();
        if (t == 0) {
            double best = -1e300, sec = -1e300;
            int bi = 0, si = 0;
            for (int ee = 0; ee < NEXP; ++ee) {
                double vv = red[0][ee] + red[1][ee] + red[2][ee] + red[3][ee];
                if (vv > best)     { sec = best; si = bi; best = vv; bi = ee; }
                else if (vv > sec) { sec = vv; si = ee; }
            }
            out[IDX_OFF + 2 * tok]     = (float)bi;
            out[IDX_OFF + 2 * tok + 1] = (float)si;
        }
        __syncthreads();
    }
}

extern "C" void kernel_launch(void* const* d_in, const int* in_sizes, int n_in,
                              void* d_out, int out_size, void* d_ws, size_t ws_size,
                              hipStream_t stream)
{
    const float* x = (const float*)d_in[0];
    const float* W = (const float*)d_in[1];
    float* out = (float*)d_out;
    float* ws  = (float*)d_ws;         // ~2.3 MB used
    short8_t* WH8 = (short8_t*)ws;
    short8_t* WL8 = (short8_t*)(ws + WS_WL);
    float* cntp = ws + WS_CNTP;
    int* rep_cnt  = (int*)(ws + WS_RCNT);
    int* rep_list = (int*)(ws + WS_RLIST);

    build_wt   <<<64, 256, 0, stream>>>(W, WH8, WL8, rep_cnt);
    router_gemm<<<NBLK, 512, 0, stream>>>(x, WH8, WL8, out, cntp, rep_cnt, rep_list);
    router_tail<<<257, 256, 0, stream>>>(x, W, out, cntp, rep_cnt, rep_list);
}

// Round 19
// 92.935 us; speedup vs baseline: 1.3580x; 1.3154x over previous
//
#include <hip/hip_runtime.h>
#include <hip/hip_bf16.h>
#include <math.h>

#define TOK_TOTAL 16384
#define D_MODEL   2048
#define NEXP      64
#define BM        64               // tokens per gemm block
#define KC        64               // k per LDS chunk
#define KHALF     1024             // split-K: half of K per block
#define NCH       (KHALF / KC)     // 16
#define PAD       72               // bf16 elems per LDS row
#define TAU       1e-3f

#define IDX_OFF   (TOK_TOTAL * NEXP)
#define LOSS_OFF  (IDX_OFF + TOK_TOTAL * 2)

// ws layout (floats): p1 [16384*64] | cntp [256*64] | rep_cnt | rep_list | scrap
#define WS_CNT    (TOK_TOTAL * NEXP)
#define WS_RCNT   (WS_CNT + TOK_TOTAL)
#define WS_RLIST  (WS_RCNT + 1)
#define WS_SCRAP  (WS_RLIST + TOK_TOTAL)

typedef __attribute__((ext_vector_type(8))) short short8_t;
typedef __attribute__((ext_vector_type(4))) float f32x4;

// ---- K0: read-bandwidth ground truth + L3 warmer ----------------------------
// m13-style pure linear sweep: wave reads 1 KB contiguous per step, device
// sweeps 16.8 MB contiguous per step, 8 steps = all 134 MB of x.
__global__ __launch_bounds__(256, 8)
void probe_read(const float* __restrict__ x, float* __restrict__ scrap)
{
    const int tid = blockIdx.x * 256 + threadIdx.x;   // 4096 blocks x 256
    const float4* x4 = (const float4*)x;
    float s = 0.f;
    #pragma unroll
    for (int i = 0; i < 8; ++i) {
        float4 v = x4[(long)tid + (long)i * (4096L * 256)];
        s += v.x + v.y + v.z + v.w;
    }
    #pragma unroll
    for (int d = 1; d < 64; d <<= 1) s += __shfl_xor(s, d, 64);
    if ((threadIdx.x & 63) == 0) scrap[tid >> 6] = s;   // keep loads live
}

// ---- K1: split-bf16 MFMA GEMM, split-K x2 (round-8 proven) ------------------
__global__ __launch_bounds__(256, 2)
void router_gemm(const float* __restrict__ x, const float* __restrict__ W,
                 float* __restrict__ p0, float* __restrict__ p1,
                 int* __restrict__ rep_cnt)
{
    __shared__ __align__(16) short lds[2][4][BM][PAD];   // 73728 B

    const int t  = threadIdx.x;
    const int w  = t >> 6;
    const int l  = t & 63;
    const int kh = blockIdx.x & 1;
    const long tok0 = (long)(blockIdx.x >> 1) * BM;
    const long kb0  = (long)kh * KHALF;

    if (blockIdx.x == 0 && t == 0) *rep_cnt = 0;

    const int sr = t >> 4;
    const int sc = (t & 15) * 4;

    f32x4 acc[4];
    #pragma unroll
    for (int nt = 0; nt < 4; ++nt) acc[nt] = (f32x4){0.f, 0.f, 0.f, 0.f};

    float4 xr[4], wr[4];

    auto LOADCH = [&](int ic) {
        const long k0 = kb0 + (long)ic * KC;
        #pragma unroll
        for (int p = 0; p < 4; ++p) {
            xr[p] = *(const float4*)(x + (tok0 + sr + 16 * p) * D_MODEL + k0 + sc);
            wr[p] = *(const float4*)(W + (long)(sr + 16 * p) * D_MODEL + k0 + sc);
        }
    };

    auto STORECH = [&](int buf) {
        #pragma unroll
        for (int p = 0; p < 4; ++p) {
            const int row = sr + 16 * p;
            const float fx[4] = {xr[p].x, xr[p].y, xr[p].z, xr[p].w};
            const float fw[4] = {wr[p].x, wr[p].y, wr[p].z, wr[p].w};
            short xh[4], xl[4], wh[4], wl[4];
            #pragma unroll
            for (int j = 0; j < 4; ++j) {
                __hip_bfloat16 h = __float2bfloat16(fx[j]);
                xh[j] = __builtin_bit_cast(short, h);
                xl[j] = __builtin_bit_cast(short, __float2bfloat16(fx[j] - __bfloat162float(h)));
                __hip_bfloat16 g = __float2bfloat16(fw[j]);
                wh[j] = __builtin_bit_cast(short, g);
                wl[j] = __builtin_bit_cast(short, __float2bfloat16(fw[j] - __bfloat162float(g)));
            }
            *(short4*)(&lds[buf][0][row][sc]) = make_short4(xh[0], xh[1], xh[2], xh[3]);
            *(short4*)(&lds[buf][1][row][sc]) = make_short4(xl[0], xl[1], xl[2], xl[3]);
            *(short4*)(&lds[buf][2][row][sc]) = make_short4(wh[0], wh[1], wh[2], wh[3]);
            *(short4*)(&lds[buf][3][row][sc]) = make_short4(wl[0], wl[1], wl[2], wl[3]);
        }
    };

    auto COMPUTE = [&](int buf) {
        const int arow = w * 16 + (l & 15);
        #pragma unroll
        for (int s = 0; s < 2; ++s) {
            const int ke = s * 32 + (l >> 4) * 8;
            short8_t ah = *(const short8_t*)(&lds[buf][0][arow][ke]);
            short8_t al = *(const short8_t*)(&lds[buf][1][arow][ke]);
            #pragma unroll
            for (int nt = 0; nt < 4; ++nt) {
                const int brow = nt * 16 + (l & 15);
                short8_t bh = *(const short8_t*)(&lds[buf][2][brow][ke]);
                short8_t bl = *(const short8_t*)(&lds[buf][3][brow][ke]);
                acc[nt] = __builtin_amdgcn_mfma_f32_16x16x32_bf16(ah, bl, acc[nt], 0, 0, 0);
                acc[nt] = __builtin_amdgcn_mfma_f32_16x16x32_bf16(al, bh, acc[nt], 0, 0, 0);
                acc[nt] = __builtin_amdgcn_mfma_f32_16x16x32_bf16(ah, bh, acc[nt], 0, 0, 0);
            }
        }
    };

    LOADCH(0);
    STORECH(0);
    __syncthreads();

    for (int ic = 0; ic < NCH; ++ic) {
        const int buf = ic & 1;
        const bool pre = (ic + 1 < NCH);
        if (pre) LOADCH(ic + 1);
        COMPUTE(buf);
        if (pre) STORECH(buf ^ 1);
        __syncthreads();
    }

    float* dst = kh ? p1 : p0;
    #pragma unroll
    for (int nt = 0; nt < 4; ++nt)
        #pragma unroll
        for (int r = 0; r < 4; ++r)
            dst[(tok0 + w * 16 + (l >> 4) * 4 + r) * NEXP + nt * 16 + (l & 15)] = acc[nt][r];
}

// -------- K2: all-register combine: top-3 via shfl merge (round-8 proven) -----
__global__ __launch_bounds__(256, 1)
void router_combine(const float* __restrict__ p0, const float* __restrict__ p1,
                    float* __restrict__ out, float* __restrict__ cntp,
                    int* __restrict__ rep_cnt, int* __restrict__ rep_list)
{
    __shared__ float4 s_ig[64];
    const int t = threadIdx.x;
    const int r = t >> 2, q = t & 3;
    const long tok0 = (long)blockIdx.x * 64;
    const long tok  = tok0 + r;

    float v[16];
    {
        const float4* a4 = (const float4*)(p0 + tok * NEXP) + q * 4;
        const float4* b4 = (const float4*)(p1 + tok * NEXP) + q * 4;
        #pragma unroll
        for (int j = 0; j < 4; ++j) {
            float4 a = a4[j], b = b4[j];
            v[j*4+0] = a.x + b.x; v[j*4+1] = a.y + b.y;
            v[j*4+2] = a.z + b.z; v[j*4+3] = a.w + b.w;
        }
    }

    float b0 = -1e30f, b1 = -1e30f, b2 = -1e30f;
    int i0 = 0, i1 = 0;
    const int ebase = q * 16;
    #pragma unroll
    for (int j = 0; j < 16; ++j) {
        float xv = v[j]; int e = ebase + j;
        if (xv > b0)      { b2 = b1; b1 = b0; i1 = i0; b0 = xv; i0 = e; }
        else if (xv > b1) { b2 = b1; b1 = xv; i1 = e; }
        else if (xv > b2) { b2 = xv; }
    }

    #pragma unroll
    for (int d = 1; d <= 2; d <<= 1) {
        float ob0 = __shfl_xor(b0, d, 64), ob1 = __shfl_xor(b1, d, 64), ob2 = __shfl_xor(b2, d, 64);
        int   oi0 = __shfl_xor(i0, d, 64), oi1 = __shfl_xor(i1, d, 64);
        bool a0w = (b0 > ob0) || (b0 == ob0 && i0 < oi0);
        float nb0 = a0w ? b0 : ob0;  int ni0 = a0w ? i0 : oi0;
        float ca  = a0w ? b1 : ob1;  int cia = a0w ? i1 : oi1;
        float cb  = a0w ? ob0 : b0;  int cib = a0w ? oi0 : i0;
        float wa2 = a0w ? b2 : ob2;
        float lb1 = a0w ? ob1 : b1;
        bool w1 = (ca > cb) || (ca == cb && cia < cib);
        float nb1 = w1 ? ca : cb;  int ni1 = w1 ? cia : cib;
        float nb2 = w1 ? fmaxf(wa2, cb) : fmaxf(ca, lb1);
        b0 = nb0; i0 = ni0; b1 = nb1; i1 = ni1; b2 = nb2;
    }

    float ex = __expf(b1 - b0);
    float g0 = 1.f / (1.f + ex);
    float g1 = ex * g0;

    {
        float* orow = out + tok * NEXP + ebase;
        #pragma unroll
        for (int j4 = 0; j4 < 4; ++j4) {
            float gv[4];
            #pragma unroll
            for (int j = 0; j < 4; ++j) {
                int e = ebase + j4 * 4 + j;
                gv[j] = (e == i0) ? g0 : ((e == i1) ? g1 : 0.f);
            }
            *(float4*)(orow + j4 * 4) = make_float4(gv[0], gv[1], gv[2], gv[3]);
        }
    }

    if (q == 0) {
        out[IDX_OFF + 2 * tok]     = (float)i0;
        out[IDX_OFF + 2 * tok + 1] = (float)i1;
        s_ig[r] = make_float4((float)i0, (float)i1, g0, g1);
        if ((b0 - b1 < TAU) || (b1 - b2 < TAU)) {
            int p = atomicAdd(rep_cnt, 1);
            rep_list[p] = (int)tok;
        }
    }
    __syncthreads();

    if (t < 64) {
        float c = 0.f;
        for (int tt = 0; tt < 64; ++tt) {
            float4 gg = s_ig[tt];
            if ((int)gg.x == t) c += gg.z;
            if ((int)gg.y == t) c += gg.w;
        }
        cntp[blockIdx.x * NEXP + t] = c;
    }
}

// -------- K3: fused tail: block 0 = loss; blocks 1.. = fp64 index repair ------
__global__ __launch_bounds__(256, 1)
void router_tail(const float* __restrict__ x, const float* __restrict__ W,
                 float* __restrict__ out, const float* __restrict__ cntp,
                 const int* __restrict__ rep_cnt, const int* __restrict__ rep_list)
{
    const int t = threadIdx.x;

    if (blockIdx.x == 0) {
        __shared__ double red[4][NEXP];
        const int e = t & 63, p = t >> 6;
        double s = 0.0;
        for (int b = 0; b < 64; ++b)
            s += (double)cntp[(p * 64 + b) * NEXP + e];
        red[p][e] = s;
        __syncthreads();
        if (t == 0) {
            double sc[NEXP], tot = 0.0;
            for (int i = 0; i < NEXP; ++i) {
                sc[i] = red[0][i] + red[1][i] + red[2][i] + red[3][i];
                tot += sc[i];
            }
            double loss = 0.0;
            for (int i = 0; i < NEXP; ++i) {
                double d = sc[i] / tot * (double)NEXP - 1.0;
                loss += d * d;
            }
            out[LOSS_OFF] = (float)(loss / NEXP);
        }
        return;
    }

    __shared__ double red[4][NEXP];
    const int nf = *rep_cnt;
    const int e = t & 63, part = t >> 6;
    for (int i = (int)blockIdx.x - 1; i < nf; i += (int)gridDim.x - 1) {
        const long tok = rep_list[i];
        const float* xr = x + tok * D_MODEL;
        const float* wr = W + (long)e * D_MODEL;
        const int k0 = part * 512;
        double s = 0.0;
        for (int kk = 0; kk < 512; kk += 4) {
            float4 xv = *(const float4*)(xr + k0 + kk);
            float4 wv = *(const float4*)(wr + k0 + kk);
            s = fma((double)xv.x, (double)wv.x, s);
            s = fma((double)xv.y, (double)wv.y, s);
            s = fma((double)xv.z, (double)wv.z, s);
            s = fma((double)xv.w, (double)wv.w, s);
        }
        red[part][e] = s;
        __syncthreads();
        if (t == 0) {
            double best = -1e300, sec = -1e300;
            int bi = 0, si = 0;
            for (int ee = 0; ee < NEXP; ++ee) {
                double vv = red[0][ee] + red[1][ee] + red[2][ee] + red[3][ee];
                if (vv > best)     { sec = best; si = bi; best = vv; bi = ee; }
                else if (vv > sec) { sec = vv; si = ee; }
            }
            out[IDX_OFF + 2 * tok]     = (float)bi;
            out[IDX_OFF + 2 * tok + 1] = (float)si;
        }
        __syncthreads();
    }
}

extern "C" void kernel_launch(void* const* d_in, const int* in_sizes, int n_in,
                              void* d_out, int out_size, void* d_ws, size_t ws_size,
                              hipStream_t stream)
{
    const float* x = (const float*)d_in[0];
    const float* W = (const float*)d_in[1];
    float* out  = (float*)d_out;
    float* ws   = (float*)d_ws;        // ~4.4 MB used
    float* p0   = out;                 // kh=0 partial parks in gates region
    float* p1   = ws;                  // kh=1 partial
    float* cntp = ws + WS_CNT;
    int*   rep_cnt  = (int*)(ws + WS_RCNT);
    int*   rep_list = (int*)(ws + WS_RLIST);
    float* scrap    = ws + WS_SCRAP;

    probe_read    <<<4096, 256, 0, stream>>>(x, scrap);
    router_gemm   <<<(TOK_TOTAL / BM) * 2, 256, 0, stream>>>(x, W, p0, p1, rep_cnt);
    router_combine<<<TOK_TOTAL / 64, 256, 0, stream>>>(p0, p1, out, cntp, rep_cnt, rep_list);
    router_tail   <<<257, 256, 0, stream>>>(x, W, out, cntp, rep_cnt, rep_list);
}